// Round 8
// baseline (176.309 us; speedup 1.0000x reference)
//
#include <hip/hip_runtime.h>

using half8   = __attribute__((ext_vector_type(8))) _Float16;
using f32x4   = __attribute__((ext_vector_type(4))) float;
using ushort8 = __attribute__((ext_vector_type(8))) unsigned short;

__device__ __forceinline__ void gload16(const void* g, void* l) {
  __builtin_amdgcn_global_load_lds(
      (const __attribute__((address_space(1))) void*)g,
      (__attribute__((address_space(3))) void*)l, 16, 0, 0);
}

// XCD-aware bijective swizzle with 8x4 2D rects. Requires gx%8==0, gy%4==0.
__device__ __forceinline__ void xcd_swizzle(int& x, int& y, int& z) {
  const int gx = gridDim.x, gy = gridDim.y;
  const int nwg = gx * gy * gridDim.z;
  const int f = blockIdx.x + gx * (blockIdx.y + gy * blockIdx.z);
  const int w = (f & 7) * (nwg >> 3) + (f >> 3);
  const int r = w >> 5, u = w & 31;
  const int nrx = gx >> 3, nry = gy >> 2;
  const int pz  = nrx * nry;
  const int rz  = r / pz, rr = r % pz;
  x = (rr % nrx) * 8 + (u & 7);
  y = (rr / nrx) * 4 + (u >> 3);
  z = rz;
}

// ---------------- cast fp32 -> fp16 ----------------
__global__ __launch_bounds__(256) void cast_f32_f16(
    const float* __restrict__ in, unsigned short* __restrict__ out, long n) {
  long i = ((long)blockIdx.x * 256 + threadIdx.x) * 8;
  if (i >= n) return;
  float4 a = *(const float4*)(in + i);
  float4 b = *(const float4*)(in + i + 4);
  union { _Float16 h[8]; ushort8 u; } r;
  r.h[0] = (_Float16)a.x; r.h[1] = (_Float16)a.y;
  r.h[2] = (_Float16)a.z; r.h[3] = (_Float16)a.w;
  r.h[4] = (_Float16)b.x; r.h[5] = (_Float16)b.y;
  r.h[6] = (_Float16)b.z; r.h[7] = (_Float16)b.w;
  *(ushort8*)(out + i) = r.u;
}

// ========= m201-faithful 8-phase NT GEMM: C[M,N] = A[M,K]*B[N,K]^T =========
// BM=256, BN=64*N_REP, BK=64, 512 thr (2M x 4N waves). Per-wave rows are
// INTERLEAVED: m-tile mt -> row mt*32 + wr*16, so phase p (m-tiles 2p,2p+1)
// consumes exactly A-quarter [64p,64p+64) -- every staging target below is
// dead one phase before its write issues.
// Iteration = 2 K-tiles (even->slot0, odd->slot1), 8 phases. Phase:
//   { ds_read A subtile (4 b128) [+ all B frags at P0/P4]; stage 1 unit;
//     s_barrier; lgkmcnt(0); setprio1; 16*N_REP/4*... (2m x N_REP x 2ks) MFMA;
//     setprio0; [P3/P7: counted vmcnt]; s_barrier }
// Stage units (A-half = 2 gload16, B0 = 2, B1 = N4:2/N3:1/N2:0):
//   P0: A1(t+1)->s1   P1: B0(t+2)->s0  P2: A0(t+2)->s0  P3: B1(t+2)->s0
//   P4: A1(t+2)->s0   P5: B0(t+3)->s1  P6: A0(t+3)->s1  P7: B1(t+3)->s1
// Fences: P3-end vmcnt(K1) guarantees tile t+1 landed (leaves t+2's B0,A0,B1
// = K1 loads in flight); P7-end vmcnt(K1) guarantees t+2 landed.
// K1 = N4:6 / N3:5 / N2:4. Never 0 in steady state (T4).
template <int MODE, int N_REP>
__global__ __launch_bounds__(512, 2) void gemm8p(
    const unsigned short* __restrict__ Ab, const unsigned short* __restrict__ Bb,
    int K, int lda, int ldb, long sA, long sB,
    void* __restrict__ o0, void* __restrict__ o1, void* __restrict__ o2) {
  constexpr int BM  = 256;
  constexpr int BN  = 64 * N_REP;
  constexpr int ASZ = BM * 64;
  constexpr int BSZ = BN * 64;
  __shared__ unsigned short lds[2 * ASZ + 2 * BSZ];

  const int tid  = threadIdx.x;
  const int lane = tid & 63;
  const int wv   = tid >> 6;
  const int wr   = wv >> 2, wc = wv & 3;
  const int fr   = lane & 15, fq = lane >> 4;
  int bxi, byi, bzi;
  xcd_swizzle(bxi, byi, bzi);
  const int bm = byi * BM;
  const int bn = bxi * BN;
  const int bz = bzi;

  const unsigned short* A = Ab + (long)bz * sA;
  const unsigned short* B = Bb + (long)bz * sB;

  // staging: thread t -> row tid>>3 in a 64-row unit, 16B granule tid&7,
  // source pre-swizzled (gload_lds writes linearly; reads apply same XOR)
  const int row_s = tid >> 3;
  const int col_s = ((tid & 7) ^ (row_s & 7)) * 8;
  const unsigned short* aS = A + (long)(bm + row_s) * lda + col_s;
  const unsigned short* bS = B + (long)(bn + row_s) * ldb + col_s;
  unsigned short* ldsA = lds;
  unsigned short* ldsB = lds + 2 * ASZ;

  const int kg0 = ((0 * 4 + fq) ^ (fr & 7)) * 16;
  const int kg1 = ((1 * 4 + fq) ^ (fr & 7)) * 16;
  const int aRd = (wr * 16 + fr) * 128;            // + mt*4096 + kg
  const int bRd = (wc * (16 * N_REP) + fr) * 128;  // + ni*2048 + kg

  f32x4 acc[8][N_REP] = {};
  half8 bf[N_REP][2];
  half8 afX[2][2], afY[2][2];

  const int nt = K / 64;

#define FENCE_K1()                                                                 \
  do {                                                                             \
    if constexpr (N_REP == 2)      asm volatile("s_waitcnt vmcnt(4)" ::: "memory");\
    else if constexpr (N_REP == 3) asm volatile("s_waitcnt vmcnt(5)" ::: "memory");\
    else                           asm volatile("s_waitcnt vmcnt(6)" ::: "memory");\
  } while (0)
#define VM0() asm volatile("s_waitcnt vmcnt(0)" ::: "memory")

#define STAGE_A01(SL, T) {                                                         \
    const long kt = (long)(T) * 64;                                                \
    unsigned short* d = ldsA + (SL) * ASZ + wv * 512;                              \
    gload16(aS + kt, d);                                                           \
    gload16(aS + (long)64 * lda + kt, d + 4096); }
#define STAGE_A23(SL, T) {                                                         \
    const long kt = (long)(T) * 64;                                                \
    unsigned short* d = ldsA + (SL) * ASZ + 8192 + wv * 512;                       \
    gload16(aS + (long)128 * lda + kt, d);                                         \
    gload16(aS + (long)192 * lda + kt, d + 4096); }
#define STAGE_B0(SL, T) {                                                          \
    const long kt = (long)(T) * 64;                                                \
    unsigned short* d = ldsB + (SL) * BSZ + wv * 512;                              \
    gload16(bS + kt, d);                                                           \
    gload16(bS + (long)64 * ldb + kt, d + 4096); }
#define STAGE_B1(SL, T)                                                            \
    if constexpr (N_REP >= 3) {                                                    \
      const long kt = (long)(T) * 64;                                              \
      unsigned short* d = ldsB + (SL) * BSZ + 8192 + wv * 512;                     \
      gload16(bS + (long)128 * ldb + kt, d);                                       \
      if constexpr (N_REP == 4) gload16(bS + (long)192 * ldb + kt, d + 4096);      \
    }

#define PH(P, AF)                                                                  \
  {                                                                                \
    constexpr int SL = ((P) >= 4) ? 1 : 0;                                         \
    const char* lA = (const char*)(ldsA + SL * ASZ);                               \
    if ((P) == 0 || (P) == 4) {                                                    \
      const char* lB = (const char*)(ldsB + SL * BSZ);                             \
      _Pragma("unroll") for (int ni = 0; ni < N_REP; ++ni) {                       \
        bf[ni][0] = *(const half8*)(lB + bRd + ni * 2048 + kg0);                   \
        bf[ni][1] = *(const half8*)(lB + bRd + ni * 2048 + kg1);                   \
      }                                                                            \
    }                                                                              \
    _Pragma("unroll") for (int i = 0; i < 2; ++i) {                                \
      AF[i][0] = *(const half8*)(lA + aRd + (2 * ((P) & 3) + i) * 4096 + kg0);     \
      AF[i][1] = *(const half8*)(lA + aRd + (2 * ((P) & 3) + i) * 4096 + kg1);     \
    }                                                                              \
    if ((P) == 0)               STAGE_A23(1, t + 1)                                \
    if ((P) == 1 && t + 2 < nt) STAGE_B0(0, t + 2)                                 \
    if ((P) == 2 && t + 2 < nt) STAGE_A01(0, t + 2)                                \
    if ((P) == 3 && t + 2 < nt) STAGE_B1(0, t + 2)                                 \
    if ((P) == 4 && t + 2 < nt) STAGE_A23(0, t + 2)                                \
    if ((P) == 5 && t + 3 < nt) STAGE_B0(1, t + 3)                                 \
    if ((P) == 6 && t + 3 < nt) STAGE_A01(1, t + 3)                                \
    if ((P) == 7 && t + 3 < nt) STAGE_B1(1, t + 3)                                 \
    __builtin_amdgcn_sched_barrier(0);                                             \
    __builtin_amdgcn_s_barrier();                                                  \
    asm volatile("s_waitcnt lgkmcnt(0)" ::: "memory");                             \
    __builtin_amdgcn_sched_barrier(0);                                             \
    __builtin_amdgcn_s_setprio(1);                                                 \
    _Pragma("unroll") for (int ks = 0; ks < 2; ++ks)                               \
    _Pragma("unroll") for (int i = 0; i < 2; ++i)                                  \
    _Pragma("unroll") for (int ni = 0; ni < N_REP; ++ni)                           \
      acc[2 * ((P) & 3) + i][ni] = __builtin_amdgcn_mfma_f32_16x16x32_f16(         \
          AF[i][ks], bf[ni][ks], acc[2 * ((P) & 3) + i][ni], 0, 0, 0);             \
    __builtin_amdgcn_s_setprio(0);                                                 \
    __builtin_amdgcn_sched_barrier(0);                                             \
    if ((P) == 3) { if (t + 2 < nt) FENCE_K1(); else VM0(); }                      \
    if ((P) == 7) { if (t + 3 < nt) FENCE_K1(); else VM0(); }                      \
    __builtin_amdgcn_s_barrier();                                                  \
  }

  // ---- prologue: tile0 full -> slot0; tile1 A0 + B -> slot1 (A1(1) at P0) ----
  STAGE_A01(0, 0)
  STAGE_A23(0, 0)
  STAGE_B0(0, 0)
  STAGE_B1(0, 0)
  STAGE_A01(1, 1)
  STAGE_B0(1, 1)
  STAGE_B1(1, 1)
  FENCE_K1();  // tile0 landed; tile1's A0+B (= K1 loads) may remain in flight
  __builtin_amdgcn_s_barrier();

  for (int t = 0; t < nt; t += 2) {
    PH(0, afX) PH(1, afY) PH(2, afX) PH(3, afY)
    PH(4, afX) PH(5, afY) PH(6, afX) PH(7, afY)
  }
#undef PH
#undef STAGE_A01
#undef STAGE_A23
#undef STAGE_B0
#undef STAGE_B1

  // epilogue: C/D 16x16 layout col=lane&15, row=fq*4+reg; wave rows interleaved
  const int row0 = bm + wr * 16 + fq * 4;
  const int col0 = bn + wc * (16 * N_REP) + fr;
#pragma unroll
  for (int mi = 0; mi < 8; ++mi) {
#pragma unroll
    for (int ni = 0; ni < N_REP; ++ni) {
      f32x4 c = acc[mi][ni];
      const long r0 = row0 + mi * 32;
      const long e  = col0 + ni * 16;
      if constexpr (MODE == 0) {
        _Float16* q  = (_Float16*)o0;
        _Float16* kk = (_Float16*)o1;
        _Float16* vv = (_Float16*)o2;
#pragma unroll
        for (int j = 0; j < 4; ++j) {
          const long i = r0 + j;
          const float val = c[j];
          if (e < 1024)      q [i * 1024 + e]          = (_Float16)(val * 0.03125f);
          else if (e < 2048) kk[i * 1024 + (e - 1024)] = (_Float16)val;
          else               vv[i * 1024 + (e - 2048)] = (_Float16)val;
        }
      } else if constexpr (MODE == 1) {
        float* C = (float*)o0 + (long)bz * 2048 * 2048;
#pragma unroll
        for (int j = 0; j < 4; ++j) C[(r0 + j) * 2048 + e] = c[j];
      } else {
        float* C = (float*)o0 + (long)bz * 2048 * 1024;
#pragma unroll
        for (int j = 0; j < 4; ++j) C[(r0 + j) * 1024 + e] = c[j];
      }
    }
  }
}

// ---------------- transpose v [b][n][d] -> vT [b][d][n] (fp16) ----------------
__global__ __launch_bounds__(256) void transpose_v(
    const unsigned short* __restrict__ v, unsigned short* __restrict__ vT) {
  __shared__ unsigned short t[64][72];  // +8 pad
  const long b = blockIdx.z;
  const unsigned short* vb = v + b * (2048L * 1024);
  unsigned short* ob = vT + b * (1024L * 2048);
  const int n0 = blockIdx.y * 64;
  const int d0 = blockIdx.x * 64;
  const int tid = threadIdx.x;
  const int r  = tid >> 2;
  const int c0 = (tid & 3) * 16;
  const unsigned short* src = vb + (long)(n0 + r) * 1024 + d0 + c0;
  *(ushort4*)&t[r][c0]      = *(const ushort4*)(src);
  *(ushort4*)&t[r][c0 + 4]  = *(const ushort4*)(src + 4);
  *(ushort4*)&t[r][c0 + 8]  = *(const ushort4*)(src + 8);
  *(ushort4*)&t[r][c0 + 12] = *(const ushort4*)(src + 12);
  __syncthreads();
  union { unsigned short h[8]; ushort8 u; } w0, w1;
#pragma unroll
  for (int j = 0; j < 8; ++j) w0.h[j] = t[c0 + j][r];
#pragma unroll
  for (int j = 0; j < 8; ++j) w1.h[j] = t[c0 + 8 + j][r];
  unsigned short* dst = ob + (long)(d0 + r) * 2048 + n0 + c0;
  *(ushort8*)dst       = w0.u;
  *(ushort8*)(dst + 8) = w1.u;
}

// ---------------- row softmax fp32[2048] -> fp16 in-place ----------------
__global__ __launch_bounds__(256) void softmax_rows(float* __restrict__ S) {
  const long row = blockIdx.x;
  float* p = S + row * 2048;
  const int t = threadIdx.x;
  float4 v0 = *(const float4*)(p + t * 8);
  float4 v1 = *(const float4*)(p + t * 8 + 4);
  float f[8] = {v0.x, v0.y, v0.z, v0.w, v1.x, v1.y, v1.z, v1.w};
  float m = f[0];
#pragma unroll
  for (int j = 1; j < 8; ++j) m = fmaxf(m, f[j]);
  for (int o = 32; o; o >>= 1) m = fmaxf(m, __shfl_xor(m, o));
  __shared__ float redm[4];
  if (!(t & 63)) redm[t >> 6] = m;
  __syncthreads();
  m = fmaxf(fmaxf(redm[0], redm[1]), fmaxf(redm[2], redm[3]));
  float e[8], s = 0.f;
#pragma unroll
  for (int j = 0; j < 8; ++j) { e[j] = __expf(f[j] - m); s += e[j]; }
  for (int o = 32; o; o >>= 1) s += __shfl_xor(s, o);
  __shared__ float reds[4];
  if (!(t & 63)) reds[t >> 6] = s;
  __syncthreads();
  s = reds[0] + reds[1] + reds[2] + reds[3];
  const float inv = 1.0f / s;
  union { _Float16 h[8]; ushort8 u; } r;
#pragma unroll
  for (int j = 0; j < 8; ++j) r.h[j] = (_Float16)(e[j] * inv);
  *(ushort8*)((unsigned short*)p + t * 8) = r.u;  // P fp16, row pitch 4096 halves
}

extern "C" void kernel_launch(void* const* d_in, const int* in_sizes, int n_in,
                              void* d_out, int out_size, void* d_ws, size_t ws_size,
                              hipStream_t stream) {
  const float* x = (const float*)d_in[0];   // [4,2048,1024]
  const float* W = (const float*)d_in[1];   // [3072,1024]
  float* out = (float*)d_out;               // [4,2048,1024] fp32
  char* ws = (char*)d_ws;

  const long MB16 = 16777216;  // 8192*1024*2 bytes
  unsigned short* q  = (unsigned short*)(ws);
  unsigned short* k  = (unsigned short*)(ws + MB16);
  unsigned short* vT = (unsigned short*)(ws + 2 * MB16);
  float*          S  = (float*)(ws + 3 * MB16);              // 64 MiB
  // aliased into S region (dead before S is written):
  unsigned short* xb = (unsigned short*)(ws + 3 * MB16);
  unsigned short* wb = (unsigned short*)(ws + 4 * MB16);
  unsigned short* v  = (unsigned short*)(ws + 4 * MB16 + 6291456);

  // 1. casts
  cast_f32_f16<<<4096, 256, 0, stream>>>(x, xb, 8388608L);
  cast_f32_f16<<<1536, 256, 0, stream>>>(W, wb, 3145728L);
  // 2. qkv = x @ W^T (M=8192, N=3072, K=1024), BM=256 BN=192 -> 512 blocks
  gemm8p<0, 3><<<dim3(16, 32, 1), 512, 0, stream>>>(
      xb, wb, 1024, 1024, 1024, 0L, 0L, q, k, v);
  // 3. v -> vT per batch
  transpose_v<<<dim3(16, 32, 4), 256, 0, stream>>>(v, vT);
  // 4. S = (q*scale) @ k^T per batch (M=N=2048, K=1024), BM=BN=256 -> 256 blocks
  gemm8p<1, 4><<<dim3(8, 8, 4), 512, 0, stream>>>(
      q, k, 1024, 1024, 1024, 2048L * 1024, 2048L * 1024, S, nullptr, nullptr);
  // 5. row softmax, P fp16 in place (row pitch 4096 halves)
  softmax_rows<<<8192, 256, 0, stream>>>(S);
  // 6. out = P @ vT^T per batch (M=2048, N=1024, K=2048), BM=256 BN=128 -> 256 blocks
  gemm8p<2, 2><<<dim3(8, 8, 4), 512, 0, stream>>>(
      (unsigned short*)S, vT, 2048, 4096, 2048, 2048L * 4096, 1024L * 2048,
      out, nullptr, nullptr);
}

// Round 9
// 171.151 us; speedup vs baseline: 1.0301x; 1.0301x over previous
//
#include <hip/hip_runtime.h>

using half8   = __attribute__((ext_vector_type(8))) _Float16;
using f32x4   = __attribute__((ext_vector_type(4))) float;
using ushort8 = __attribute__((ext_vector_type(8))) unsigned short;

__device__ __forceinline__ void gload16(const void* g, void* l) {
  __builtin_amdgcn_global_load_lds(
      (const __attribute__((address_space(1))) void*)g,
      (__attribute__((address_space(3))) void*)l, 16, 0, 0);
}

// XCD-aware bijective swizzle with 8x4 2D rects. Requires gx%8==0, gy%4==0.
__device__ __forceinline__ void xcd_swizzle(int& x, int& y, int& z) {
  const int gx = gridDim.x, gy = gridDim.y;
  const int nwg = gx * gy * gridDim.z;
  const int f = blockIdx.x + gx * (blockIdx.y + gy * blockIdx.z);
  const int w = (f & 7) * (nwg >> 3) + (f >> 3);
  const int r = w >> 5, u = w & 31;
  const int nrx = gx >> 3, nry = gy >> 2;
  const int pz  = nrx * nry;
  const int rz  = r / pz, rr = r % pz;
  x = (rr % nrx) * 8 + (u & 7);
  y = (rr / nrx) * 4 + (u >> 3);
  z = rz;
}

// ---------------- cast fp32 -> fp16 ----------------
__global__ __launch_bounds__(256) void cast_f32_f16(
    const float* __restrict__ in, unsigned short* __restrict__ out, long n) {
  long i = ((long)blockIdx.x * 256 + threadIdx.x) * 8;
  if (i >= n) return;
  float4 a = *(const float4*)(in + i);
  float4 b = *(const float4*)(in + i + 4);
  union { _Float16 h[8]; ushort8 u; } r;
  r.h[0] = (_Float16)a.x; r.h[1] = (_Float16)a.y;
  r.h[2] = (_Float16)a.z; r.h[3] = (_Float16)a.w;
  r.h[4] = (_Float16)b.x; r.h[5] = (_Float16)b.y;
  r.h[6] = (_Float16)b.z; r.h[7] = (_Float16)b.w;
  *(ushort8*)(out + i) = r.u;
}

// ======== 4-wave, 2-blocks/CU, one-barrier-per-tile NT GEMM ========
// C[M,N] = A[M,K]*B[N,K]^T. BM=BN=128, BK=64, 256 threads (2Mx2N waves),
// per-wave 64x64 = 4m x 4n MFMA 16x16x32. LDS 64 KB (2 dbuf slots A+B)
// -> 2 independent blocks/CU: TLP covers each block's barrier/drain stalls
// (the overlap that 1-block/CU 8-wave configs structurally lack).
// Tile body: read B frags + A m-tiles 0,1; stage tile t+1 (8 gload16, issue->
// drain distance = full tile >> HBM latency); MFMA m0 | read m2 | MFMA m1 |
// read m3 | MFMA m2 | MFMA m3; vmcnt(0); s_barrier. Compiler inserts counted
// lgkm waits between reads and MFMAs. Slot safety as R7 (reads of slot s all
// complete before B_t because the MFMAs consuming them precede B_t).
template <int MODE>
__global__ __launch_bounds__(256, 2) void gemm4w(
    const unsigned short* __restrict__ Ab, const unsigned short* __restrict__ Bb,
    int K, int lda, int ldb, long sA, long sB,
    void* __restrict__ o0, void* __restrict__ o1, void* __restrict__ o2) {
  constexpr int ASZ = 128 * 64;  // halves per slot
  constexpr int BSZ = 128 * 64;
  __shared__ unsigned short lds[2 * ASZ + 2 * BSZ];  // 64 KB

  const int tid  = threadIdx.x;
  const int lane = tid & 63;
  const int wv   = tid >> 6;
  const int wr   = wv >> 1, wc = wv & 1;
  const int fr   = lane & 15, fq = lane >> 4;
  int bxi, byi, bzi;
  xcd_swizzle(bxi, byi, bzi);
  const int bm = byi * 128;
  const int bn = bxi * 128;
  const int bz = bzi;

  const unsigned short* A = Ab + (long)bz * sA;
  const unsigned short* B = Bb + (long)bz * sB;

  // staging: thread t -> row tid>>3 (0..31) per 32-row issue, granule tid&7,
  // source pre-swizzled (gload_lds writes linearly; reads apply same XOR)
  const int row_s = tid >> 3;
  const int col_s = ((tid & 7) ^ (row_s & 7)) * 8;
  const unsigned short* aS = A + (long)(bm + row_s) * lda + col_s;
  const unsigned short* bS = B + (long)(bn + row_s) * ldb + col_s;
  unsigned short* ldsA = lds;
  unsigned short* ldsB = lds + 2 * ASZ;

  // read offsets (bytes); row&7 == fr&7 for all fragment rows
  const int kg0 = ((0 * 4 + fq) ^ (fr & 7)) * 16;
  const int kg1 = ((1 * 4 + fq) ^ (fr & 7)) * 16;
  const int aRd = (wr * 64 + fr) * 128;  // + mi*2048 + kg
  const int bRd = (wc * 64 + fr) * 128;  // + ni*2048 + kg

  f32x4 acc[4][4] = {};
  half8 bf[4][2];
  half8 a0[2], a1[2], a2[2], a3[2];

  const int nt = K / 64;

#define STAGE_T(SL, T)                                                             \
  {                                                                                \
    const long kt = (long)(T) * 64;                                                \
    unsigned short* dA = ldsA + (SL) * ASZ + wv * 512;                             \
    unsigned short* dB = ldsB + (SL) * BSZ + wv * 512;                             \
    _Pragma("unroll") for (int i = 0; i < 4; ++i)                                  \
      gload16(aS + (long)(i * 32) * lda + kt, dA + i * 2048);                      \
    _Pragma("unroll") for (int i = 0; i < 4; ++i)                                  \
      gload16(bS + (long)(i * 32) * ldb + kt, dB + i * 2048);                      \
  }
#define RDA(DST, MI)                                                               \
  DST[0] = *(const half8*)(lA + aRd + (MI) * 2048 + kg0);                          \
  DST[1] = *(const half8*)(lA + aRd + (MI) * 2048 + kg1);
#define MFMAQ(MI, AA)                                                              \
  __builtin_amdgcn_s_setprio(1);                                                   \
  _Pragma("unroll") for (int ks = 0; ks < 2; ++ks)                                 \
  _Pragma("unroll") for (int ni = 0; ni < 4; ++ni)                                 \
    acc[MI][ni] = __builtin_amdgcn_mfma_f32_16x16x32_f16(                          \
        AA[ks], bf[ni][ks], acc[MI][ni], 0, 0, 0);                                 \
  __builtin_amdgcn_s_setprio(0);

  // ---- prologue: stage tile 0 into slot 0 ----
  STAGE_T(0, 0)
  asm volatile("s_waitcnt vmcnt(0)" ::: "memory");
  __builtin_amdgcn_s_barrier();
  __builtin_amdgcn_sched_barrier(0);

  for (int t = 0; t < nt; ++t) {
    const int s = t & 1;
    const char* lA = (const char*)(ldsA + s * ASZ);
    const char* lB = (const char*)(ldsB + s * BSZ);
#pragma unroll
    for (int ni = 0; ni < 4; ++ni) {
      bf[ni][0] = *(const half8*)(lB + bRd + ni * 2048 + kg0);
      bf[ni][1] = *(const half8*)(lB + bRd + ni * 2048 + kg1);
    }
    RDA(a0, 0)
    RDA(a1, 1)
    if (t + 1 < nt) STAGE_T(s ^ 1, t + 1)
    MFMAQ(0, a0)
    RDA(a2, 2)
    MFMAQ(1, a1)
    RDA(a3, 3)
    MFMAQ(2, a2)
    MFMAQ(3, a3)
    asm volatile("s_waitcnt vmcnt(0)" ::: "memory");
    __builtin_amdgcn_s_barrier();
    __builtin_amdgcn_sched_barrier(0);
  }
#undef STAGE_T
#undef RDA
#undef MFMAQ

  // epilogue: C/D layout col=lane&15, row=fq*4+reg
  const int row0 = bm + wr * 64 + fq * 4;
  const int col0 = bn + wc * 64 + fr;
#pragma unroll
  for (int mi = 0; mi < 4; ++mi) {
#pragma unroll
    for (int ni = 0; ni < 4; ++ni) {
      f32x4 c = acc[mi][ni];
      const long r0 = row0 + mi * 16;
      const long e  = col0 + ni * 16;
      if constexpr (MODE == 0) {
        _Float16* q  = (_Float16*)o0;
        _Float16* kk = (_Float16*)o1;
        _Float16* vv = (_Float16*)o2;
#pragma unroll
        for (int j = 0; j < 4; ++j) {
          const long i = r0 + j;
          const float val = c[j];
          if (e < 1024)      q [i * 1024 + e]          = (_Float16)(val * 0.03125f);
          else if (e < 2048) kk[i * 1024 + (e - 1024)] = (_Float16)val;
          else               vv[i * 1024 + (e - 2048)] = (_Float16)val;
        }
      } else if constexpr (MODE == 1) {
        float* C = (float*)o0 + (long)bz * 2048 * 2048;
#pragma unroll
        for (int j = 0; j < 4; ++j) C[(r0 + j) * 2048 + e] = c[j];
      } else {
        float* C = (float*)o0 + (long)bz * 2048 * 1024;
#pragma unroll
        for (int j = 0; j < 4; ++j) C[(r0 + j) * 1024 + e] = c[j];
      }
    }
  }
}

// ---------------- transpose v [b][n][d] -> vT [b][d][n] (fp16) ----------------
__global__ __launch_bounds__(256) void transpose_v(
    const unsigned short* __restrict__ v, unsigned short* __restrict__ vT) {
  __shared__ unsigned short t[64][72];  // +8 pad
  const long b = blockIdx.z;
  const unsigned short* vb = v + b * (2048L * 1024);
  unsigned short* ob = vT + b * (1024L * 2048);
  const int n0 = blockIdx.y * 64;
  const int d0 = blockIdx.x * 64;
  const int tid = threadIdx.x;
  const int r  = tid >> 2;
  const int c0 = (tid & 3) * 16;
  const unsigned short* src = vb + (long)(n0 + r) * 1024 + d0 + c0;
  *(ushort4*)&t[r][c0]      = *(const ushort4*)(src);
  *(ushort4*)&t[r][c0 + 4]  = *(const ushort4*)(src + 4);
  *(ushort4*)&t[r][c0 + 8]  = *(const ushort4*)(src + 8);
  *(ushort4*)&t[r][c0 + 12] = *(const ushort4*)(src + 12);
  __syncthreads();
  union { unsigned short h[8]; ushort8 u; } w0, w1;
#pragma unroll
  for (int j = 0; j < 8; ++j) w0.h[j] = t[c0 + j][r];
#pragma unroll
  for (int j = 0; j < 8; ++j) w1.h[j] = t[c0 + 8 + j][r];
  unsigned short* dst = ob + (long)(d0 + r) * 2048 + n0 + c0;
  *(ushort8*)dst       = w0.u;
  *(ushort8*)(dst + 8) = w1.u;
}

// ---------------- row softmax fp32[2048] -> fp16 in-place ----------------
__global__ __launch_bounds__(256) void softmax_rows(float* __restrict__ S) {
  const long row = blockIdx.x;
  float* p = S + row * 2048;
  const int t = threadIdx.x;
  float4 v0 = *(const float4*)(p + t * 8);
  float4 v1 = *(const float4*)(p + t * 8 + 4);
  float f[8] = {v0.x, v0.y, v0.z, v0.w, v1.x, v1.y, v1.z, v1.w};
  float m = f[0];
#pragma unroll
  for (int j = 1; j < 8; ++j) m = fmaxf(m, f[j]);
  for (int o = 32; o; o >>= 1) m = fmaxf(m, __shfl_xor(m, o));
  __shared__ float redm[4];
  if (!(t & 63)) redm[t >> 6] = m;
  __syncthreads();
  m = fmaxf(fmaxf(redm[0], redm[1]), fmaxf(redm[2], redm[3]));
  float e[8], s = 0.f;
#pragma unroll
  for (int j = 0; j < 8; ++j) { e[j] = __expf(f[j] - m); s += e[j]; }
  for (int o = 32; o; o >>= 1) s += __shfl_xor(s, o);
  __shared__ float reds[4];
  if (!(t & 63)) reds[t >> 6] = s;
  __syncthreads();
  s = reds[0] + reds[1] + reds[2] + reds[3];
  const float inv = 1.0f / s;
  union { _Float16 h[8]; ushort8 u; } r;
#pragma unroll
  for (int j = 0; j < 8; ++j) r.h[j] = (_Float16)(e[j] * inv);
  *(ushort8*)((unsigned short*)p + t * 8) = r.u;  // P fp16, row pitch 4096 halves
}

extern "C" void kernel_launch(void* const* d_in, const int* in_sizes, int n_in,
                              void* d_out, int out_size, void* d_ws, size_t ws_size,
                              hipStream_t stream) {
  const float* x = (const float*)d_in[0];   // [4,2048,1024]
  const float* W = (const float*)d_in[1];   // [3072,1024]
  float* out = (float*)d_out;               // [4,2048,1024] fp32
  char* ws = (char*)d_ws;

  const long MB16 = 16777216;  // 8192*1024*2 bytes
  unsigned short* q  = (unsigned short*)(ws);
  unsigned short* k  = (unsigned short*)(ws + MB16);
  unsigned short* vT = (unsigned short*)(ws + 2 * MB16);
  float*          S  = (float*)(ws + 3 * MB16);              // 64 MiB
  // aliased into S region (dead before S is written):
  unsigned short* xb = (unsigned short*)(ws + 3 * MB16);
  unsigned short* wb = (unsigned short*)(ws + 4 * MB16);
  unsigned short* v  = (unsigned short*)(ws + 4 * MB16 + 6291456);

  // 1. casts
  cast_f32_f16<<<4096, 256, 0, stream>>>(x, xb, 8388608L);
  cast_f32_f16<<<1536, 256, 0, stream>>>(W, wb, 3145728L);
  // 2. qkv = x @ W^T (M=8192, N=3072, K=1024): 24x64 = 1536 blocks
  gemm4w<0><<<dim3(24, 64, 1), 256, 0, stream>>>(
      xb, wb, 1024, 1024, 1024, 0L, 0L, q, k, v);
  // 3. v -> vT per batch
  transpose_v<<<dim3(16, 32, 4), 256, 0, stream>>>(v, vT);
  // 4. S = (q*scale) @ k^T per batch (M=N=2048, K=1024): 16x16x4 = 1024 blocks
  gemm4w<1><<<dim3(16, 16, 4), 256, 0, stream>>>(
      q, k, 1024, 1024, 1024, 2048L * 1024, 2048L * 1024, S, nullptr, nullptr);
  // 5. row softmax, P fp16 in place (row pitch 4096 halves)
  softmax_rows<<<8192, 256, 0, stream>>>(S);
  // 6. out = P @ vT^T per batch (M=2048, N=1024, K=2048): 8x16x4 = 512 blocks
  gemm4w<2><<<dim3(8, 16, 4), 256, 0, stream>>>(
      (unsigned short*)S, vT, 2048, 4096, 2048, 2048L * 4096, 1024L * 2048,
      out, nullptr, nullptr);
}